// Round 6
// baseline (18047.754 us; speedup 1.0000x reference)
//
#include <hip/hip_runtime.h>
#include <cstdint>
#include <cstddef>

// ---------------------------------------------------------------------------
// LSTMModel: embed(mask pad=0) -> LSTM(128->256) -> LSTM(256->256) -> FC(256->64) -> softmax
// B=64 T=2048 D=128 H=256 4H=1024 OUT=64 V=1000
//
// Round 6: r5's "resident" weights were silently re-streamed (VGPR_Count=64:
// 16-wave WG capped the allocator at 128 regs/lane; 100-reg array + working
// set didn't fit). Fix: 256-thread WG (1 wave/SIMD -> 512 VGPR budget),
// thread j owns ALL 4 gate rows of unit j:
//   - 28 chunks/row x 4 rows in VGPRs (448 regs), 4 chunks/row in LDS (64KB
//     manual spill, read only by owner thread)
//   - gates thread-local -> no gsh exchange; ONE barrier/step; h parity-
//     double-buffered in LDS (hsh[2][256])
//   - per-step floor: 512 v_dot2 = 1024 cyc/SIMD, LDS pipe ~1150 cyc overlapped
// Verification hook: VGPR_Count must be >440, else compiler punted again.
// Fallback: r5 streaming kernel if dynamic-LDS attr fails.
//  - GEMM/embed/fc/chunking unchanged (passed, ~0.3ms total)
// ---------------------------------------------------------------------------

typedef _Float16 half_t;
typedef _Float16 half8 __attribute__((ext_vector_type(8)));
typedef _Float16 half2t __attribute__((ext_vector_type(2)));
typedef float floatx4 __attribute__((ext_vector_type(4)));

#define B_   64
#define T_   2048
#define D_   128
#define H_   256
#define G4_  1024
#define OUT_ 64
#define MTOT (B_ * T_)

#define EVC2 28                          // VGPR-resident chunks per row (of 32)
#define TLC2 4                           // LDS-resident chunks per row
#define TL2_BYTES (TLC2 * 4 * 256 * 16)  // 64 KB dynamic LDS

#if defined(__has_builtin)
#if __has_builtin(__builtin_amdgcn_fdot2)
#define HAVE_FDOT2 1
#endif
#endif

__device__ __forceinline__ float dot2acc(unsigned w, unsigned h, float acc) {
  half2t a = __builtin_bit_cast(half2t, w);
  half2t b = __builtin_bit_cast(half2t, h);
#ifdef HAVE_FDOT2
  return __builtin_amdgcn_fdot2(a, b, acc, false);
#else
  return acc + (float)a[0] * (float)b[0] + (float)a[1] * (float)b[1];
#endif
}

__device__ __forceinline__ float fast_sigmoid(float x) {
  return 1.f / (1.f + __expf(-x));
}
__device__ __forceinline__ float fast_tanh(float x) {
  return 1.f - 2.f / (1.f + __expf(2.f * x));
}

// ---------------- prep kernels ----------------

__global__ __launch_bounds__(256) void k_cvt_f16(const float* __restrict__ in,
                                                 half_t* __restrict__ out, int n) {
  int i = blockIdx.x * 256 + threadIdx.x;
  if (i < n) out[i] = (half_t)in[i];
}

// r5-style pack (for fallback streaming kernel):
// wp[(kc*1024 + j)*8 + e] = Whh[j][kc*8+e]
__global__ __launch_bounds__(256) void k_pack_whh(const float* __restrict__ whh,
                                                  half_t* __restrict__ wp) {
  int i = blockIdx.x * 256 + threadIdx.x;      // 262144 total
  int e  = i & 7;
  int j  = (i >> 3) & 1023;
  int kc = i >> 13;
  wp[i] = (half_t)whh[j * 256 + kc * 8 + e];
}

// r6 pack for unit-per-thread kernel:
// wq[((rr*32 + kc)*256 + j)*8 + e] = Whh[rr*256 + j][kc*8 + e]
// -> per (rr,kc): 256 consecutive threads load consecutive uint4 (coalesced)
__global__ __launch_bounds__(256) void k_pack_whh_q(const float* __restrict__ whh,
                                                    half_t* __restrict__ wq) {
  int i = blockIdx.x * 256 + threadIdx.x;      // 262144 total
  int e  = i & 7;
  int j  = (i >> 3) & 255;
  int kc = (i >> 11) & 31;
  int rr = (i >> 16) & 3;
  wq[i] = (half_t)whh[(rr * 256 + j) * 256 + kc * 8 + e];
}

__global__ __launch_bounds__(256) void k_bias(const float* __restrict__ a,
                                              const float* __restrict__ b,
                                              float* __restrict__ out, int n) {
  int i = blockIdx.x * 256 + threadIdx.x;
  if (i < n) out[i] = a[i] + b[i];
}

// fc_W [64][256] -> fcwt[k*64 + l] = fc_W[l][k]
__global__ __launch_bounds__(256) void k_fcwt(const float* __restrict__ fcw,
                                              float* __restrict__ fcwt) {
  int i = blockIdx.x * 256 + threadIdx.x;      // 16384 total
  fcwt[i] = fcw[(i & 63) * 256 + (i >> 6)];
}

// ---------------- embedding ----------------

__global__ __launch_bounds__(256) void k_embed(const int* __restrict__ x,
                                               const float* __restrict__ tab,
                                               half_t* __restrict__ e) {
  const long i = (long)blockIdx.x * 256 + threadIdx.x;
  const long m = i >> 4;
  const int ch = (int)(i & 15) * 8;
  const int xi = x[m];
  half8 v;
  #pragma unroll
  for (int q = 0; q < 8; ++q) v[q] = (half_t)0.f;
  if (xi != 0) {
    const float* p = tab + (long)xi * D_ + ch;
    #pragma unroll
    for (int q = 0; q < 8; ++q) v[q] = (half_t)p[q];
  }
  *(half8*)(e + m * D_ + ch) = v;
}

// ---------------- f16 MFMA GEMM (unchanged, passed) ----------------

__global__ __launch_bounds__(256) void k_gemm_f16(const half_t* __restrict__ A,
                                                  const half_t* __restrict__ Wt,
                                                  const float* __restrict__ bias,
                                                  half_t* __restrict__ C,
                                                  int K, int N,
                                                  int rowShift, int strideB, int toff) {
  __shared__ half_t As[128][40];
  __shared__ half_t Bs[128][40];
  const int tid  = threadIdx.x;
  const int lane = tid & 63;
  const int wave = tid >> 6;
  const int wr = wave >> 1, wc = wave & 1;
  const int r0 = blockIdx.x * 128;
  const int n0 = blockIdx.y * 128;
  const int srow = tid >> 2;
  const int schunk = (tid & 3) * 8;
  const int rmask = (1 << rowShift) - 1;

  floatx4 zero = {0.f, 0.f, 0.f, 0.f};
  floatx4 acc[4][4];
  for (int i = 0; i < 4; ++i)
    for (int j = 0; j < 4; ++j) acc[i][j] = zero;

  const int ra = r0 + srow, rb = r0 + srow + 64;
  const half_t* ArowA = A + ((long)(ra >> rowShift) * strideB + toff + (ra & rmask)) * K;
  const half_t* ArowB = A + ((long)(rb >> rowShift) * strideB + toff + (rb & rmask)) * K;

  for (int k0 = 0; k0 < K; k0 += 32) {
    *(uint4*)(&As[srow][schunk])      = *(const uint4*)(ArowA + k0 + schunk);
    *(uint4*)(&As[srow + 64][schunk]) = *(const uint4*)(ArowB + k0 + schunk);
    const half_t* Bp = Wt + (long)(n0 + srow) * K + k0 + schunk;
    *(uint4*)(&Bs[srow][schunk])      = *(const uint4*)(Bp);
    *(uint4*)(&Bs[srow + 64][schunk]) = *(const uint4*)(Bp + 64L * K);
    __syncthreads();

    const int kq = (lane >> 4) * 8;
    const int fr = lane & 15;
    half8 af[4], bf[4];
    #pragma unroll
    for (int i = 0; i < 4; ++i) af[i] = *(const half8*)(&As[wr * 64 + i * 16 + fr][kq]);
    #pragma unroll
    for (int i = 0; i < 4; ++i) bf[i] = *(const half8*)(&Bs[wc * 64 + i * 16 + fr][kq]);
    #pragma unroll
    for (int mi = 0; mi < 4; ++mi)
      #pragma unroll
      for (int ni = 0; ni < 4; ++ni)
        acc[mi][ni] = __builtin_amdgcn_mfma_f32_16x16x32_f16(af[mi], bf[ni], acc[mi][ni], 0, 0, 0);
    __syncthreads();
  }

  const int fr = lane & 15, fq = lane >> 4;
  for (int ni = 0; ni < 4; ++ni) {
    const int gcol = n0 + wc * 64 + ni * 16 + fr;
    const float bv = bias[gcol];
    for (int mi = 0; mi < 4; ++mi) {
      const long grow = r0 + wr * 64 + mi * 16 + fq * 4;
      #pragma unroll
      for (int r = 0; r < 4; ++r)
        C[(grow + r) * (long)N + gcol] = (half_t)(acc[mi][ni][r] + bv);
    }
  }
}

// ---------------- LSTM recurrence: unit-per-thread, fully resident ----------------
// 256 threads (4 waves, 1/SIMD -> 512 VGPR/lane). Thread j owns unit j:
// gate rows {j, 256+j, 512+j, 768+j}. Chunks 0..27 of each row in VGPRs
// (448 regs), chunks 28..31 in dynamic LDS (owner-read manual spill).
// h parity-double-buffered in static LDS; one barrier per step.

__global__ __launch_bounds__(256, 1) void k_lstm_res2(const half_t* __restrict__ xg,
                                                      const uint4* __restrict__ Wq,
                                                      half_t* __restrict__ hout,
                                                      float* __restrict__ c_state,
                                                      half_t* __restrict__ h_state,
                                                      int steps, int first) {
  extern __shared__ uint4 wtail[];            // [TLC2*4][256]
  __shared__ __align__(16) half_t hsh[2][256];
  const int b = blockIdx.x;
  const int j = threadIdx.x;                  // unit index 0..255

  // one-time residency load (coalesced): VGPR part + LDS tail
  uint4 wv[4 * EVC2];
  #pragma unroll
  for (int rr = 0; rr < 4; ++rr)
    #pragma unroll
    for (int kc = 0; kc < EVC2; ++kc)
      wv[rr * EVC2 + kc] = Wq[(rr * 32 + kc) * 256 + j];
  #pragma unroll
  for (int rr = 0; rr < 4; ++rr)
    #pragma unroll
    for (int cc = 0; cc < TLC2; ++cc)
      wtail[(cc * 4 + rr) * 256 + j] = Wq[(rr * 32 + EVC2 + cc) * 256 + j];

  float c = 0.f;
  if (first) {
    hsh[0][j] = (half_t)0.f;
  } else {
    hsh[0][j] = h_state[b * H_ + j];
    c = c_state[b * H_ + j];
  }
  __syncthreads();

  const half_t* xp = xg + (long)b * steps * G4_ + j;
  half_t* hp_out = hout + (long)b * steps * H_ + j;
  half_t hlast = hsh[0][j];

  for (int t = 0; t < steps; ++t) {
    // xg loads issued early; consumed ~1000 cyc later after the dot phase
    const half_t* xr = xp + (long)t * G4_;
    float x0 = (float)xr[0];
    float x1 = (float)xr[256];
    float x2 = (float)xr[512];
    float x3 = (float)xr[768];

    const uint4* hb = (const uint4*)hsh[t & 1];
    float a0 = 0.f, a1 = 0.f, a2 = 0.f, a3 = 0.f;
    #pragma unroll
    for (int kc = 0; kc < 32; ++kc) {
      uint4 h4 = hb[kc];                      // wave-broadcast LDS read
      uint4 w0, w1, w2, w3;
      if (kc < EVC2) {
        w0 = wv[0 * EVC2 + kc];
        w1 = wv[1 * EVC2 + kc];
        w2 = wv[2 * EVC2 + kc];
        w3 = wv[3 * EVC2 + kc];
      } else {
        w0 = wtail[((kc - EVC2) * 4 + 0) * 256 + j];
        w1 = wtail[((kc - EVC2) * 4 + 1) * 256 + j];
        w2 = wtail[((kc - EVC2) * 4 + 2) * 256 + j];
        w3 = wtail[((kc - EVC2) * 4 + 3) * 256 + j];
      }
      a0 = dot2acc(w0.x, h4.x, a0); a0 = dot2acc(w0.y, h4.y, a0);
      a0 = dot2acc(w0.z, h4.z, a0); a0 = dot2acc(w0.w, h4.w, a0);
      a1 = dot2acc(w1.x, h4.x, a1); a1 = dot2acc(w1.y, h4.y, a1);
      a1 = dot2acc(w1.z, h4.z, a1); a1 = dot2acc(w1.w, h4.w, a1);
      a2 = dot2acc(w2.x, h4.x, a2); a2 = dot2acc(w2.y, h4.y, a2);
      a2 = dot2acc(w2.z, h4.z, a2); a2 = dot2acc(w2.w, h4.w, a2);
      a3 = dot2acc(w3.x, h4.x, a3); a3 = dot2acc(w3.y, h4.y, a3);
      a3 = dot2acc(w3.z, h4.z, a3); a3 = dot2acc(w3.w, h4.w, a3);
    }

    // thread-local gates (PyTorch order i,f,g,o)
    float ig = fast_sigmoid(a0 + x0);
    float fg = fast_sigmoid(a1 + x1);
    float g2 = fast_tanh(a2 + x2);
    float og = fast_sigmoid(a3 + x3);
    c = fg * c + ig * g2;
    float h = og * fast_tanh(c);
    half_t hh = (half_t)h;
    hp_out[(long)t * H_] = hh;
    hsh[(t + 1) & 1][j] = hh;                 // parity buffer: no race w/ readers
    hlast = hh;
    __syncthreads();                          // h(t) visible for step t+1
  }
  c_state[b * H_ + j] = c;
  h_state[b * H_ + j] = hlast;
}

// ---------------- r5 streaming recurrence (fallback) ----------------

__global__ __launch_bounds__(1024) void k_lstm(const half_t* __restrict__ xg,
                                               const uint4* __restrict__ Wp,
                                               half_t* __restrict__ hout,
                                               float* __restrict__ c_state,
                                               half_t* __restrict__ h_state,
                                               int steps, int first) {
  const int b = blockIdx.x;
  const int j = threadIdx.x;
  __shared__ float gsh[1024];
  __shared__ __align__(16) half_t hsh[256];
  float c = 0.f;
  if (j < H_) {
    if (first) {
      hsh[j] = (half_t)0.f;
    } else {
      hsh[j] = h_state[b * H_ + j];
      c = c_state[b * H_ + j];
    }
  }
  const uint4*  wp     = Wp + j;
  const half_t* xp     = xg + (long)b * steps * G4_ + j;
  half_t*       hp_out = hout + (long)b * steps * H_;
  for (int t = 0; t < steps; ++t) {
    __syncthreads();
    float acc = (float)xp[(long)t * G4_];
    const uint4* hv4 = (const uint4*)hsh;
    #pragma unroll 8
    for (int kc = 0; kc < 32; ++kc) {
      uint4 w  = wp[(long)kc * G4_];
      uint4 h4 = hv4[kc];
      acc = dot2acc(w.x, h4.x, acc);
      acc = dot2acc(w.y, h4.y, acc);
      acc = dot2acc(w.z, h4.z, acc);
      acc = dot2acc(w.w, h4.w, acc);
    }
    gsh[j] = acc;
    __syncthreads();
    if (j < H_) {
      float ig = fast_sigmoid(gsh[j]);
      float fg = fast_sigmoid(gsh[H_ + j]);
      float g2 = fast_tanh(gsh[2 * H_ + j]);
      float og = fast_sigmoid(gsh[3 * H_ + j]);
      c = fg * c + ig * g2;
      float h = og * fast_tanh(c);
      hp_out[(long)t * H_ + j] = (half_t)h;
      hsh[j] = (half_t)h;
    }
  }
  if (j < H_) {
    c_state[b * H_ + j] = c;
    h_state[b * H_ + j] = hsh[j];
  }
}

// ---------------- FC + softmax (unchanged) ----------------

__global__ __launch_bounds__(256) void k_fc_softmax(const half_t* __restrict__ h2,
                                                    const float* __restrict__ fcwt,
                                                    const float* __restrict__ fcb,
                                                    float* __restrict__ out,
                                                    int rowShift, int strideB, int toff) {
  const int lane = threadIdx.x & 63;
  const int r = blockIdx.x * 4 + (threadIdx.x >> 6);
  const half_t* hr = h2 + (long)r * H_;
  float acc = fcb[lane];
  for (int kc = 0; kc < 32; ++kc) {
    uint4 hv = *(const uint4*)(hr + kc * 8);
    unsigned hu[4] = {hv.x, hv.y, hv.z, hv.w};
    #pragma unroll
    for (int p = 0; p < 4; ++p) {
      half2t hh = __builtin_bit_cast(half2t, hu[p]);
      acc += (float)hh[0] * fcwt[(kc * 8 + p * 2) * 64 + lane];
      acc += (float)hh[1] * fcwt[(kc * 8 + p * 2 + 1) * 64 + lane];
    }
  }
  float m = acc;
  #pragma unroll
  for (int off = 32; off > 0; off >>= 1) m = fmaxf(m, __shfl_xor(m, off));
  float e = __expf(acc - m);
  float s = e;
  #pragma unroll
  for (int off = 32; off > 0; off >>= 1) s += __shfl_xor(s, off);
  const long outrow = (long)(r >> rowShift) * strideB + toff + (r & ((1 << rowShift) - 1));
  out[outrow * OUT_ + lane] = e / s;
}

// ---------------- launch ----------------

extern "C" void kernel_launch(void* const* d_in, const int* in_sizes, int n_in,
                              void* d_out, int out_size, void* d_ws, size_t ws_size,
                              hipStream_t stream) {
  const int*   x    = (const int*)d_in[0];
  const float* tab  = (const float*)d_in[1];
  const float* wih0 = (const float*)d_in[2];
  const float* whh0 = (const float*)d_in[3];
  const float* bih0 = (const float*)d_in[4];
  const float* bhh0 = (const float*)d_in[5];
  const float* wih1 = (const float*)d_in[6];
  const float* whh1 = (const float*)d_in[7];
  const float* bih1 = (const float*)d_in[8];
  const float* bhh1 = (const float*)d_in[9];
  const float* fcw  = (const float*)d_in[10];
  const float* fcb  = (const float*)d_in[11];

  char* p = (char*)d_ws;
  auto alloc = [&](size_t bytes) {
    void* r = (void*)p;
    p += (bytes + 255) & ~(size_t)255;
    return r;
  };
  half_t* wih0_h = (half_t*)alloc((size_t)G4_ * D_ * 2);
  half_t* wih1_h = (half_t*)alloc((size_t)G4_ * H_ * 2);
  half_t* wq0    = (half_t*)alloc((size_t)G4_ * H_ * 2);   // r6 pack
  half_t* wq1    = (half_t*)alloc((size_t)G4_ * H_ * 2);
  half_t* wp0    = (half_t*)alloc((size_t)G4_ * H_ * 2);   // r5 pack (fallback)
  half_t* wp1    = (half_t*)alloc((size_t)G4_ * H_ * 2);
  float*  bias0  = (float*)alloc(G4_ * 4);
  float*  bias1  = (float*)alloc(G4_ * 4);
  float*  fcwt   = (float*)alloc((size_t)H_ * OUT_ * 4);
  half_t* hstate = (half_t*)alloc((size_t)2 * B_ * H_ * 2);
  float*  cstate = (float*)alloc((size_t)2 * B_ * H_ * 4);
  size_t fixed_used = (size_t)(p - (char*)d_ws);

  // Chunk length: largest power-of-2 CH <= 2048 with XG+HB fitting in ws.
  int CH = 2048;
  while (CH > 32 &&
         fixed_used + (size_t)CH * (131072 + 32768) + (1u << 20) > ws_size)
    CH >>= 1;
  const int rowShift = __builtin_ctz(CH);
  half_t* XG = (half_t*)alloc((size_t)CH * B_ * G4_ * 2);
  half_t* HB = (half_t*)alloc((size_t)CH * B_ * H_ * 2);
  half_t* ebuf = (half_t*)d_out;   // 32MB == out bytes; rows consumed before FC writes

  hipError_t attr_rc = hipFuncSetAttribute(
      reinterpret_cast<const void*>(k_lstm_res2),
      hipFuncAttributeMaxDynamicSharedMemorySize, TL2_BYTES);
  const bool use_res = (attr_rc == hipSuccess);

  // prep (tiny)
  k_cvt_f16<<<512, 256, 0, stream>>>(wih0, wih0_h, G4_ * D_);
  k_cvt_f16<<<1024, 256, 0, stream>>>(wih1, wih1_h, G4_ * H_);
  k_pack_whh_q<<<1024, 256, 0, stream>>>(whh0, wq0);
  k_pack_whh_q<<<1024, 256, 0, stream>>>(whh1, wq1);
  k_pack_whh<<<1024, 256, 0, stream>>>(whh0, wp0);
  k_pack_whh<<<1024, 256, 0, stream>>>(whh1, wp1);
  k_bias<<<4, 256, 0, stream>>>(bih0, bhh0, bias0, G4_);
  k_bias<<<4, 256, 0, stream>>>(bih1, bhh1, bias1, G4_);
  k_fcwt<<<64, 256, 0, stream>>>(fcw, fcwt);

  k_embed<<<MTOT * (D_ / 8) / 256, 256, 0, stream>>>(x, tab, ebuf);

  const int M = B_ * CH;
  const int nchunks = T_ / CH;
  for (int ci = 0; ci < nchunks; ++ci) {
    const int t0 = ci * CH;
    k_gemm_f16<<<dim3(M / 128, G4_ / 128), 256, 0, stream>>>(
        ebuf, wih0_h, bias0, XG, D_, G4_, rowShift, T_, t0);
    if (use_res)
      k_lstm_res2<<<B_, 256, TL2_BYTES, stream>>>(XG, (const uint4*)wq0, HB,
                                                  cstate, hstate, CH, ci == 0);
    else
      k_lstm<<<B_, 1024, 0, stream>>>(XG, (const uint4*)wp0, HB,
                                      cstate, hstate, CH, ci == 0);
    k_gemm_f16<<<dim3(M / 128, G4_ / 128), 256, 0, stream>>>(
        HB, wih1_h, bias1, XG, H_, G4_, rowShift, CH, 0);
    if (use_res)
      k_lstm_res2<<<B_, 256, TL2_BYTES, stream>>>(XG, (const uint4*)wq1, HB,
                                                  cstate + B_ * H_, hstate + B_ * H_,
                                                  CH, ci == 0);
    else
      k_lstm<<<B_, 1024, 0, stream>>>(XG, (const uint4*)wp1, HB,
                                      cstate + B_ * H_, hstate + B_ * H_,
                                      CH, ci == 0);
    k_fc_softmax<<<M / 4, 256, 0, stream>>>(HB, fcwt, fcb, (float*)d_out,
                                            rowShift, T_, t0);
  }
}

// Round 7
// 11921.135 us; speedup vs baseline: 1.5139x; 1.5139x over previous
//
#include <hip/hip_runtime.h>
#include <cstdint>
#include <cstddef>

// ---------------------------------------------------------------------------
// LSTMModel: embed(mask pad=0) -> LSTM(128->256) -> LSTM(256->256) -> FC(256->64) -> softmax
// B=64 T=2048 D=128 H=256 4H=1024 OUT=64 V=1000
//
// Round 7: r6 proved arch-VGPR cap = 256/lane (448-reg v_dot2 array ->
// scratch spill, 4.4ms/dispatch). The only >256-reg residency is AGPRs,
// consumed by MFMA (r4 precedent: 128-reg A-frag array -> VGPR_Count 92,
// frags in AGPRs, numerics verified). This round: r4's MFMA matvec with
// ONE WG per batch (intra-WG barriers only; r4's cross-WG sync was the
// 23.6us/step killer, NOT the MFMA path).
//   - 64 WGs x 256 thr; wave w owns gate-quarter rows [w*256, w*256+256)
//     = 16 row-tiles x 8 k-chunks = 128 A-frags; 104 in regs (416 -> AGPR),
//     24 in 96KB dynamic LDS
//   - per step: 8 broadcast ds_read_b128 B-frags (all cols = h, verified),
//     128 MFMA/wave, col-0 extract -> gsh, barrier, thread-local gates,
//     h -> parity-buffered LDS, barrier.  ~0.35us/step predicted.
//   - fallback: r3/r5 streaming kernel if dynamic-LDS attr fails
//  - GEMM/embed/fc/chunking unchanged (passed, ~0.3ms total)
// ---------------------------------------------------------------------------

typedef _Float16 half_t;
typedef _Float16 half8 __attribute__((ext_vector_type(8)));
typedef _Float16 half2t __attribute__((ext_vector_type(2)));
typedef float floatx4 __attribute__((ext_vector_type(4)));

#define B_   64
#define T_   2048
#define D_   128
#define H_   256
#define G4_  1024
#define OUT_ 64
#define MTOT (B_ * T_)

#define RFRAGS 104                          // A-frags kept in registers per wave
#define LFRAGS 24                           // A-frags kept in LDS per wave (128 total)
#define LDSW_BYTES (4 * LFRAGS * 64 * 16)   // 96 KB dynamic LDS

#if defined(__has_builtin)
#if __has_builtin(__builtin_amdgcn_fdot2)
#define HAVE_FDOT2 1
#endif
#endif

__device__ __forceinline__ float dot2acc(unsigned w, unsigned h, float acc) {
  half2t a = __builtin_bit_cast(half2t, w);
  half2t b = __builtin_bit_cast(half2t, h);
#ifdef HAVE_FDOT2
  return __builtin_amdgcn_fdot2(a, b, acc, false);
#else
  return acc + (float)a[0] * (float)b[0] + (float)a[1] * (float)b[1];
#endif
}

__device__ __forceinline__ float fast_sigmoid(float x) {
  return 1.f / (1.f + __expf(-x));
}
__device__ __forceinline__ float fast_tanh(float x) {
  return 1.f - 2.f / (1.f + __expf(2.f * x));
}

// ---------------- prep kernels ----------------

__global__ __launch_bounds__(256) void k_cvt_f16(const float* __restrict__ in,
                                                 half_t* __restrict__ out, int n) {
  int i = blockIdx.x * 256 + threadIdx.x;
  if (i < n) out[i] = (half_t)in[i];
}

// streaming pack (fallback kernel): wp[(kc*1024 + j)*8 + e] = Whh[j][kc*8+e]
__global__ __launch_bounds__(256) void k_pack_whh(const float* __restrict__ whh,
                                                  half_t* __restrict__ wp) {
  int i = blockIdx.x * 256 + threadIdx.x;      // 262144 total
  int e  = i & 7;
  int j  = (i >> 3) & 1023;
  int kc = i >> 13;
  wp[i] = (half_t)whh[j * 256 + kc * 8 + e];
}

// MFMA A-frag pack: frag index f = w*128 + rt*8 + kc, lane l, elem e:
// wqf[(f*64 + l)*8 + e] = Whh[w*256 + rt*16 + (l&15)][kc*32 + (l>>4)*8 + e]
__global__ __launch_bounds__(256) void k_pack_whh_frag(const float* __restrict__ whh,
                                                       half_t* __restrict__ wqf) {
  int i = blockIdx.x * 256 + threadIdx.x;      // 262144 total
  int e  = i & 7;
  int l  = (i >> 3) & 63;
  int kc = (i >> 9) & 7;
  int rt = (i >> 12) & 15;
  int w  = (i >> 16) & 3;
  int row = w * 256 + rt * 16 + (l & 15);
  int col = kc * 32 + (l >> 4) * 8 + e;
  wqf[i] = (half_t)whh[row * 256 + col];
}

__global__ __launch_bounds__(256) void k_bias(const float* __restrict__ a,
                                              const float* __restrict__ b,
                                              float* __restrict__ out, int n) {
  int i = blockIdx.x * 256 + threadIdx.x;
  if (i < n) out[i] = a[i] + b[i];
}

// fc_W [64][256] -> fcwt[k*64 + l] = fc_W[l][k]
__global__ __launch_bounds__(256) void k_fcwt(const float* __restrict__ fcw,
                                              float* __restrict__ fcwt) {
  int i = blockIdx.x * 256 + threadIdx.x;      // 16384 total
  fcwt[i] = fcw[(i & 63) * 256 + (i >> 6)];
}

// ---------------- embedding ----------------

__global__ __launch_bounds__(256) void k_embed(const int* __restrict__ x,
                                               const float* __restrict__ tab,
                                               half_t* __restrict__ e) {
  const long i = (long)blockIdx.x * 256 + threadIdx.x;
  const long m = i >> 4;
  const int ch = (int)(i & 15) * 8;
  const int xi = x[m];
  half8 v;
  #pragma unroll
  for (int q = 0; q < 8; ++q) v[q] = (half_t)0.f;
  if (xi != 0) {
    const float* p = tab + (long)xi * D_ + ch;
    #pragma unroll
    for (int q = 0; q < 8; ++q) v[q] = (half_t)p[q];
  }
  *(half8*)(e + m * D_ + ch) = v;
}

// ---------------- f16 MFMA GEMM (unchanged, passed) ----------------

__global__ __launch_bounds__(256) void k_gemm_f16(const half_t* __restrict__ A,
                                                  const half_t* __restrict__ Wt,
                                                  const float* __restrict__ bias,
                                                  half_t* __restrict__ C,
                                                  int K, int N,
                                                  int rowShift, int strideB, int toff) {
  __shared__ half_t As[128][40];
  __shared__ half_t Bs[128][40];
  const int tid  = threadIdx.x;
  const int lane = tid & 63;
  const int wave = tid >> 6;
  const int wr = wave >> 1, wc = wave & 1;
  const int r0 = blockIdx.x * 128;
  const int n0 = blockIdx.y * 128;
  const int srow = tid >> 2;
  const int schunk = (tid & 3) * 8;
  const int rmask = (1 << rowShift) - 1;

  floatx4 zero = {0.f, 0.f, 0.f, 0.f};
  floatx4 acc[4][4];
  for (int i = 0; i < 4; ++i)
    for (int j = 0; j < 4; ++j) acc[i][j] = zero;

  const int ra = r0 + srow, rb = r0 + srow + 64;
  const half_t* ArowA = A + ((long)(ra >> rowShift) * strideB + toff + (ra & rmask)) * K;
  const half_t* ArowB = A + ((long)(rb >> rowShift) * strideB + toff + (rb & rmask)) * K;

  for (int k0 = 0; k0 < K; k0 += 32) {
    *(uint4*)(&As[srow][schunk])      = *(const uint4*)(ArowA + k0 + schunk);
    *(uint4*)(&As[srow + 64][schunk]) = *(const uint4*)(ArowB + k0 + schunk);
    const half_t* Bp = Wt + (long)(n0 + srow) * K + k0 + schunk;
    *(uint4*)(&Bs[srow][schunk])      = *(const uint4*)(Bp);
    *(uint4*)(&Bs[srow + 64][schunk]) = *(const uint4*)(Bp + 64L * K);
    __syncthreads();

    const int kq = (lane >> 4) * 8;
    const int fr = lane & 15;
    half8 af[4], bf[4];
    #pragma unroll
    for (int i = 0; i < 4; ++i) af[i] = *(const half8*)(&As[wr * 64 + i * 16 + fr][kq]);
    #pragma unroll
    for (int i = 0; i < 4; ++i) bf[i] = *(const half8*)(&Bs[wc * 64 + i * 16 + fr][kq]);
    #pragma unroll
    for (int mi = 0; mi < 4; ++mi)
      #pragma unroll
      for (int ni = 0; ni < 4; ++ni)
        acc[mi][ni] = __builtin_amdgcn_mfma_f32_16x16x32_f16(af[mi], bf[ni], acc[mi][ni], 0, 0, 0);
    __syncthreads();
  }

  const int fr = lane & 15, fq = lane >> 4;
  for (int ni = 0; ni < 4; ++ni) {
    const int gcol = n0 + wc * 64 + ni * 16 + fr;
    const float bv = bias[gcol];
    for (int mi = 0; mi < 4; ++mi) {
      const long grow = r0 + wr * 64 + mi * 16 + fq * 4;
      #pragma unroll
      for (int r = 0; r < 4; ++r)
        C[(grow + r) * (long)N + gcol] = (half_t)(acc[mi][ni][r] + bv);
    }
  }
}

// ---------------- LSTM recurrence: AGPR-resident MFMA matvec, 1 WG/batch ----------------
// 256 thr (4 waves, 1/SIMD). Wave w owns rows [w*256, w*256+256) (= gate w,
// units 0..255, gate-major: i,f,g,o). 128 A-frags/wave: 104 in regs (AGPRs),
// 24 in dynamic LDS. B-frag = h broadcast to all 16 cols; C col 0 extracted.

__global__ __launch_bounds__(256, 1) void k_lstm_v3(const half_t* __restrict__ xg,
                                                    const uint4* __restrict__ wqf,
                                                    half_t* __restrict__ hout,
                                                    float* __restrict__ c_state,
                                                    half_t* __restrict__ h_state,
                                                    int steps, int first) {
  extern __shared__ uint4 wlds[];                 // [4][LFRAGS][64]
  __shared__ __align__(16) half_t hsh[2][256];
  __shared__ __align__(16) float gsh[1024];
  const int b = blockIdx.x;
  const int tid = threadIdx.x;
  const int w = tid >> 6, l = tid & 63;
  const int j = tid;

  // one-time residency: 104 frags -> registers (AGPR-backed), 24 -> LDS
  half8 wv[RFRAGS];
  const uint4* wbase = wqf + (size_t)w * 128 * 64;
  #pragma unroll
  for (int i = 0; i < RFRAGS; ++i)
    wv[i] = __builtin_bit_cast(half8, wbase[i * 64 + l]);
  #pragma unroll
  for (int i = 0; i < LFRAGS; ++i)
    wlds[(w * LFRAGS + i) * 64 + l] = wbase[(RFRAGS + i) * 64 + l];

  float c = 0.f;
  if (first) {
    hsh[0][j] = (half_t)0.f;
  } else {
    hsh[0][j] = h_state[b * H_ + j];
    c = c_state[b * H_ + j];
  }
  __syncthreads();

  const half_t* xgb = xg + (long)b * steps * G4_;
  half_t* hp_out = hout + (long)b * steps * H_ + j;

  for (int t = 0; t < steps; ++t) {
    // xg preacts for this thread's unit (issued early, consumed after MFMA)
    const half_t* xr = xgb + (long)t * G4_;
    float x0 = (float)xr[j];
    float x1 = (float)xr[256 + j];
    float x2 = (float)xr[512 + j];
    float x3 = (float)xr[768 + j];

    // B-frags: h(t-1) broadcast to all 16 cols (per-16-lane-group ds read)
    const half_t* hp = hsh[t & 1];
    half8 bf[8];
    #pragma unroll
    for (int kc = 0; kc < 8; ++kc)
      bf[kc] = *(const half8*)(hp + kc * 32 + ((l >> 4) << 3));

    // 13 register row-tiles
    #pragma unroll
    for (int rt = 0; rt < 13; ++rt) {
      floatx4 acc = {0.f, 0.f, 0.f, 0.f};
      #pragma unroll
      for (int kc = 0; kc < 8; ++kc)
        acc = __builtin_amdgcn_mfma_f32_16x16x32_f16(wv[rt * 8 + kc], bf[kc], acc, 0, 0, 0);
      if ((l & 15) == 0)
        *(floatx4*)&gsh[w * 256 + rt * 16 + ((l >> 4) << 2)] = acc;
    }
    // 3 LDS row-tiles
    #pragma unroll
    for (int rt = 13; rt < 16; ++rt) {
      floatx4 acc = {0.f, 0.f, 0.f, 0.f};
      #pragma unroll
      for (int kc = 0; kc < 8; ++kc) {
        half8 wf = __builtin_bit_cast(half8,
            wlds[(w * LFRAGS + (rt - 13) * 8 + kc) * 64 + l]);
        acc = __builtin_amdgcn_mfma_f32_16x16x32_f16(wf, bf[kc], acc, 0, 0, 0);
      }
      if ((l & 15) == 0)
        *(floatx4*)&gsh[w * 256 + rt * 16 + ((l >> 4) << 2)] = acc;
    }
    __syncthreads();                  // B1: gsh complete (and hsh[t&1] reads done)

    // thread-local gates for unit j (gate-major rows: i,f,g,o)
    float gi = gsh[j]       + x0;
    float gf = gsh[256 + j] + x1;
    float gg = gsh[512 + j] + x2;
    float go = gsh[768 + j] + x3;
    float ig = fast_sigmoid(gi);
    float fg = fast_sigmoid(gf);
    float g2 = fast_tanh(gg);
    float og = fast_sigmoid(go);
    c = fg * c + ig * g2;
    float h = og * fast_tanh(c);
    half_t hh = (half_t)h;
    hp_out[(long)t * H_] = hh;
    hsh[(t + 1) & 1][j] = hh;         // parity buffer
    __syncthreads();                  // B2: h(t) visible for step t+1
  }
  c_state[b * H_ + j] = c;
  h_state[b * H_ + j] = (half_t)hsh[steps & 1][j];
}

// ---------------- r3/r5 streaming recurrence (fallback) ----------------

__global__ __launch_bounds__(1024) void k_lstm(const half_t* __restrict__ xg,
                                               const uint4* __restrict__ Wp,
                                               half_t* __restrict__ hout,
                                               float* __restrict__ c_state,
                                               half_t* __restrict__ h_state,
                                               int steps, int first) {
  const int b = blockIdx.x;
  const int j = threadIdx.x;
  __shared__ float gsh[1024];
  __shared__ __align__(16) half_t hsh[256];
  float c = 0.f;
  if (j < H_) {
    if (first) {
      hsh[j] = (half_t)0.f;
    } else {
      hsh[j] = h_state[b * H_ + j];
      c = c_state[b * H_ + j];
    }
  }
  const uint4*  wp     = Wp + j;
  const half_t* xp     = xg + (long)b * steps * G4_ + j;
  half_t*       hp_out = hout + (long)b * steps * H_;
  for (int t = 0; t < steps; ++t) {
    __syncthreads();
    float acc = (float)xp[(long)t * G4_];
    const uint4* hv4 = (const uint4*)hsh;
    #pragma unroll 8
    for (int kc = 0; kc < 32; ++kc) {
      uint4 w  = wp[(long)kc * G4_];
      uint4 h4 = hv4[kc];
      acc = dot2acc(w.x, h4.x, acc);
      acc = dot2acc(w.y, h4.y, acc);
      acc = dot2acc(w.z, h4.z, acc);
      acc = dot2acc(w.w, h4.w, acc);
    }
    gsh[j] = acc;
    __syncthreads();
    if (j < H_) {
      float ig = fast_sigmoid(gsh[j]);
      float fg = fast_sigmoid(gsh[H_ + j]);
      float g2 = fast_tanh(gsh[2 * H_ + j]);
      float og = fast_sigmoid(gsh[3 * H_ + j]);
      c = fg * c + ig * g2;
      float h = og * fast_tanh(c);
      hp_out[(long)t * H_ + j] = (half_t)h;
      hsh[j] = (half_t)h;
    }
  }
  if (j < H_) {
    c_state[b * H_ + j] = c;
    h_state[b * H_ + j] = hsh[j];
  }
}

// ---------------- FC + softmax (unchanged) ----------------

__global__ __launch_bounds__(256) void k_fc_softmax(const half_t* __restrict__ h2,
                                                    const float* __restrict__ fcwt,
                                                    const float* __restrict__ fcb,
                                                    float* __restrict__ out,
                                                    int rowShift, int strideB, int toff) {
  const int lane = threadIdx.x & 63;
  const int r = blockIdx.x * 4 + (threadIdx.x >> 6);
  const half_t* hr = h2 + (long)r * H_;
  float acc = fcb[lane];
  for (int kc = 0; kc < 32; ++kc) {
    uint4 hv = *(const uint4*)(hr + kc * 8);
    unsigned hu[4] = {hv.x, hv.y, hv.z, hv.w};
    #pragma unroll
    for (int p = 0; p < 4; ++p) {
      half2t hh = __builtin_bit_cast(half2t, hu[p]);
      acc += (float)hh[0] * fcwt[(kc * 8 + p * 2) * 64 + lane];
      acc += (float)hh[1] * fcwt[(kc * 8 + p * 2 + 1) * 64 + lane];
    }
  }
  float m = acc;
  #pragma unroll
  for (int off = 32; off > 0; off >>= 1) m = fmaxf(m, __shfl_xor(m, off));
  float e = __expf(acc - m);
  float s = e;
  #pragma unroll
  for (int off = 32; off > 0; off >>= 1) s += __shfl_xor(s, off);
  const long outrow = (long)(r >> rowShift) * strideB + toff + (r & ((1 << rowShift) - 1));
  out[outrow * OUT_ + lane] = e / s;
}

// ---------------- launch ----------------

extern "C" void kernel_launch(void* const* d_in, const int* in_sizes, int n_in,
                              void* d_out, int out_size, void* d_ws, size_t ws_size,
                              hipStream_t stream) {
  const int*   x    = (const int*)d_in[0];
  const float* tab  = (const float*)d_in[1];
  const float* wih0 = (const float*)d_in[2];
  const float* whh0 = (const float*)d_in[3];
  const float* bih0 = (const float*)d_in[4];
  const float* bhh0 = (const float*)d_in[5];
  const float* wih1 = (const float*)d_in[6];
  const float* whh1 = (const float*)d_in[7];
  const float* bih1 = (const float*)d_in[8];
  const float* bhh1 = (const float*)d_in[9];
  const float* fcw  = (const float*)d_in[10];
  const float* fcb  = (const float*)d_in[11];

  char* p = (char*)d_ws;
  auto alloc = [&](size_t bytes) {
    void* r = (void*)p;
    p += (bytes + 255) & ~(size_t)255;
    return r;
  };
  half_t* wih0_h = (half_t*)alloc((size_t)G4_ * D_ * 2);
  half_t* wih1_h = (half_t*)alloc((size_t)G4_ * H_ * 2);
  half_t* wqf0   = (half_t*)alloc((size_t)G4_ * H_ * 2);   // frag pack
  half_t* wqf1   = (half_t*)alloc((size_t)G4_ * H_ * 2);
  half_t* wp0    = (half_t*)alloc((size_t)G4_ * H_ * 2);   // streaming pack (fallback)
  half_t* wp1    = (half_t*)alloc((size_t)G4_ * H_ * 2);
  float*  bias0  = (float*)alloc(G4_ * 4);
  float*  bias1  = (float*)alloc(G4_ * 4);
  float*  fcwt   = (float*)alloc((size_t)H_ * OUT_ * 4);
  half_t* hstate = (half_t*)alloc((size_t)2 * B_ * H_ * 2);
  float*  cstate = (float*)alloc((size_t)2 * B_ * H_ * 4);
  size_t fixed_used = (size_t)(p - (char*)d_ws);

  // Chunk length: largest power-of-2 CH <= 2048 with XG+HB fitting in ws.
  int CH = 2048;
  while (CH > 32 &&
         fixed_used + (size_t)CH * (131072 + 32768) + (1u << 20) > ws_size)
    CH >>= 1;
  const int rowShift = __builtin_ctz(CH);
  half_t* XG = (half_t*)alloc((size_t)CH * B_ * G4_ * 2);
  half_t* HB = (half_t*)alloc((size_t)CH * B_ * H_ * 2);
  half_t* ebuf = (half_t*)d_out;   // 32MB == out bytes; rows consumed before FC writes

  hipError_t attr_rc = hipFuncSetAttribute(
      reinterpret_cast<const void*>(k_lstm_v3),
      hipFuncAttributeMaxDynamicSharedMemorySize, LDSW_BYTES);
  const bool use_res = (attr_rc == hipSuccess);

  // prep (tiny)
  k_cvt_f16<<<512, 256, 0, stream>>>(wih0, wih0_h, G4_ * D_);
  k_cvt_f16<<<1024, 256, 0, stream>>>(wih1, wih1_h, G4_ * H_);
  k_pack_whh_frag<<<1024, 256, 0, stream>>>(whh0, wqf0);
  k_pack_whh_frag<<<1024, 256, 0, stream>>>(whh1, wqf1);
  k_pack_whh<<<1024, 256, 0, stream>>>(whh0, wp0);
  k_pack_whh<<<1024, 256, 0, stream>>>(whh1, wp1);
  k_bias<<<4, 256, 0, stream>>>(bih0, bhh0, bias0, G4_);
  k_bias<<<4, 256, 0, stream>>>(bih1, bhh1, bias1, G4_);
  k_fcwt<<<64, 256, 0, stream>>>(fcw, fcwt);

  k_embed<<<MTOT * (D_ / 8) / 256, 256, 0, stream>>>(x, tab, ebuf);

  const int M = B_ * CH;
  const int nchunks = T_ / CH;
  for (int ci = 0; ci < nchunks; ++ci) {
    const int t0 = ci * CH;
    k_gemm_f16<<<dim3(M / 128, G4_ / 128), 256, 0, stream>>>(
        ebuf, wih0_h, bias0, XG, D_, G4_, rowShift, T_, t0);
    if (use_res)
      k_lstm_v3<<<B_, 256, LDSW_BYTES, stream>>>(XG, (const uint4*)wqf0, HB,
                                                 cstate, hstate, CH, ci == 0);
    else
      k_lstm<<<B_, 1024, 0, stream>>>(XG, (const uint4*)wp0, HB,
                                      cstate, hstate, CH, ci == 0);
    k_gemm_f16<<<dim3(M / 128, G4_ / 128), 256, 0, stream>>>(
        HB, wih1_h, bias1, XG, H_, G4_, rowShift, CH, 0);
    if (use_res)
      k_lstm_v3<<<B_, 256, LDSW_BYTES, stream>>>(XG, (const uint4*)wqf1, HB,
                                                 cstate + B_ * H_, hstate + B_ * H_,
                                                 CH, ci == 0);
    else
      k_lstm<<<B_, 1024, 0, stream>>>(XG, (const uint4*)wp1, HB,
                                      cstate + B_ * H_, hstate + B_ * H_,
                                      CH, ci == 0);
    k_fc_softmax<<<M / 4, 256, 0, stream>>>(HB, fcwt, fcb, (float*)d_out,
                                            rowShift, T_, t0);
  }
}

// Round 8
// 10308.109 us; speedup vs baseline: 1.7508x; 1.1565x over previous
//
#include <hip/hip_runtime.h>
#include <cstdint>
#include <cstddef>

// ---------------------------------------------------------------------------
// LSTMModel: embed(mask pad=0) -> LSTM(128->256) -> LSTM(256->256) -> FC(256->64) -> softmax
// B=64 T=2048 D=128 H=256 4H=1024 OUT=64 V=1000
//
// Round 8: r7 achieved AGPR residency (no spill) but ran 2.81us/step with
// MfmaUtil 7.6% == pure MFMA issue time -> the rt-outer/kc-inner loop made
// 16 sequential 8-deep DEPENDENT mfma chains (1 wave/SIMD, nothing hides
// latency). Fix: kc-OUTER loop over two groups of 8 row-tiles -> 8
// independent acc chains, issue-bound (~615cyc). Reg rebudget: frags
// 104->96 in regs (384) + 32/wave in LDS (128KB dyn), acc 8x4=32,
// total ~490 <= 512 (no spill expected; tripwire = WRITE_SIZE > 32.9MB).
//   - layouts/pack identical to r7 (numerically verified r4/r7)
//   - fallback: r3/r5 streaming kernel if dynamic-LDS attr fails
//  - GEMM/embed/fc/chunking unchanged (passed, ~0.3ms total)
// ---------------------------------------------------------------------------

typedef _Float16 half_t;
typedef _Float16 half8 __attribute__((ext_vector_type(8)));
typedef _Float16 half2t __attribute__((ext_vector_type(2)));
typedef float floatx4 __attribute__((ext_vector_type(4)));

#define B_   64
#define T_   2048
#define D_   128
#define H_   256
#define G4_  1024
#define OUT_ 64
#define MTOT (B_ * T_)

#define RFRAGS3 96                            // A-frags in registers per wave (rts 0..11)
#define LFRAGS3 32                            // A-frags in LDS per wave (rts 12..15)
#define LDS3_BYTES (4 * LFRAGS3 * 64 * 16)    // 128 KB dynamic LDS

#if defined(__has_builtin)
#if __has_builtin(__builtin_amdgcn_fdot2)
#define HAVE_FDOT2 1
#endif
#endif

__device__ __forceinline__ float dot2acc(unsigned w, unsigned h, float acc) {
  half2t a = __builtin_bit_cast(half2t, w);
  half2t b = __builtin_bit_cast(half2t, h);
#ifdef HAVE_FDOT2
  return __builtin_amdgcn_fdot2(a, b, acc, false);
#else
  return acc + (float)a[0] * (float)b[0] + (float)a[1] * (float)b[1];
#endif
}

__device__ __forceinline__ float fast_sigmoid(float x) {
  return 1.f / (1.f + __expf(-x));
}
__device__ __forceinline__ float fast_tanh(float x) {
  return 1.f - 2.f / (1.f + __expf(2.f * x));
}

// ---------------- prep kernels ----------------

__global__ __launch_bounds__(256) void k_cvt_f16(const float* __restrict__ in,
                                                 half_t* __restrict__ out, int n) {
  int i = blockIdx.x * 256 + threadIdx.x;
  if (i < n) out[i] = (half_t)in[i];
}

// streaming pack (fallback kernel): wp[(kc*1024 + j)*8 + e] = Whh[j][kc*8+e]
__global__ __launch_bounds__(256) void k_pack_whh(const float* __restrict__ whh,
                                                  half_t* __restrict__ wp) {
  int i = blockIdx.x * 256 + threadIdx.x;      // 262144 total
  int e  = i & 7;
  int j  = (i >> 3) & 1023;
  int kc = i >> 13;
  wp[i] = (half_t)whh[j * 256 + kc * 8 + e];
}

// MFMA A-frag pack: frag index f = w*128 + rt*8 + kc, lane l, elem e:
// wqf[(f*64 + l)*8 + e] = Whh[w*256 + rt*16 + (l&15)][kc*32 + (l>>4)*8 + e]
__global__ __launch_bounds__(256) void k_pack_whh_frag(const float* __restrict__ whh,
                                                       half_t* __restrict__ wqf) {
  int i = blockIdx.x * 256 + threadIdx.x;      // 262144 total
  int e  = i & 7;
  int l  = (i >> 3) & 63;
  int kc = (i >> 9) & 7;
  int rt = (i >> 12) & 15;
  int w  = (i >> 16) & 3;
  int row = w * 256 + rt * 16 + (l & 15);
  int col = kc * 32 + (l >> 4) * 8 + e;
  wqf[i] = (half_t)whh[row * 256 + col];
}

__global__ __launch_bounds__(256) void k_bias(const float* __restrict__ a,
                                              const float* __restrict__ b,
                                              float* __restrict__ out, int n) {
  int i = blockIdx.x * 256 + threadIdx.x;
  if (i < n) out[i] = a[i] + b[i];
}

// fc_W [64][256] -> fcwt[k*64 + l] = fc_W[l][k]
__global__ __launch_bounds__(256) void k_fcwt(const float* __restrict__ fcw,
                                              float* __restrict__ fcwt) {
  int i = blockIdx.x * 256 + threadIdx.x;      // 16384 total
  fcwt[i] = fcw[(i & 63) * 256 + (i >> 6)];
}

// ---------------- embedding ----------------

__global__ __launch_bounds__(256) void k_embed(const int* __restrict__ x,
                                               const float* __restrict__ tab,
                                               half_t* __restrict__ e) {
  const long i = (long)blockIdx.x * 256 + threadIdx.x;
  const long m = i >> 4;
  const int ch = (int)(i & 15) * 8;
  const int xi = x[m];
  half8 v;
  #pragma unroll
  for (int q = 0; q < 8; ++q) v[q] = (half_t)0.f;
  if (xi != 0) {
    const float* p = tab + (long)xi * D_ + ch;
    #pragma unroll
    for (int q = 0; q < 8; ++q) v[q] = (half_t)p[q];
  }
  *(half8*)(e + m * D_ + ch) = v;
}

// ---------------- f16 MFMA GEMM (unchanged, passed) ----------------

__global__ __launch_bounds__(256) void k_gemm_f16(const half_t* __restrict__ A,
                                                  const half_t* __restrict__ Wt,
                                                  const float* __restrict__ bias,
                                                  half_t* __restrict__ C,
                                                  int K, int N,
                                                  int rowShift, int strideB, int toff) {
  __shared__ half_t As[128][40];
  __shared__ half_t Bs[128][40];
  const int tid  = threadIdx.x;
  const int lane = tid & 63;
  const int wave = tid >> 6;
  const int wr = wave >> 1, wc = wave & 1;
  const int r0 = blockIdx.x * 128;
  const int n0 = blockIdx.y * 128;
  const int srow = tid >> 2;
  const int schunk = (tid & 3) * 8;
  const int rmask = (1 << rowShift) - 1;

  floatx4 zero = {0.f, 0.f, 0.f, 0.f};
  floatx4 acc[4][4];
  for (int i = 0; i < 4; ++i)
    for (int j = 0; j < 4; ++j) acc[i][j] = zero;

  const int ra = r0 + srow, rb = r0 + srow + 64;
  const half_t* ArowA = A + ((long)(ra >> rowShift) * strideB + toff + (ra & rmask)) * K;
  const half_t* ArowB = A + ((long)(rb >> rowShift) * strideB + toff + (rb & rmask)) * K;

  for (int k0 = 0; k0 < K; k0 += 32) {
    *(uint4*)(&As[srow][schunk])      = *(const uint4*)(ArowA + k0 + schunk);
    *(uint4*)(&As[srow + 64][schunk]) = *(const uint4*)(ArowB + k0 + schunk);
    const half_t* Bp = Wt + (long)(n0 + srow) * K + k0 + schunk;
    *(uint4*)(&Bs[srow][schunk])      = *(const uint4*)(Bp);
    *(uint4*)(&Bs[srow + 64][schunk]) = *(const uint4*)(Bp + 64L * K);
    __syncthreads();

    const int kq = (lane >> 4) * 8;
    const int fr = lane & 15;
    half8 af[4], bf[4];
    #pragma unroll
    for (int i = 0; i < 4; ++i) af[i] = *(const half8*)(&As[wr * 64 + i * 16 + fr][kq]);
    #pragma unroll
    for (int i = 0; i < 4; ++i) bf[i] = *(const half8*)(&Bs[wc * 64 + i * 16 + fr][kq]);
    #pragma unroll
    for (int mi = 0; mi < 4; ++mi)
      #pragma unroll
      for (int ni = 0; ni < 4; ++ni)
        acc[mi][ni] = __builtin_amdgcn_mfma_f32_16x16x32_f16(af[mi], bf[ni], acc[mi][ni], 0, 0, 0);
    __syncthreads();
  }

  const int fr = lane & 15, fq = lane >> 4;
  for (int ni = 0; ni < 4; ++ni) {
    const int gcol = n0 + wc * 64 + ni * 16 + fr;
    const float bv = bias[gcol];
    for (int mi = 0; mi < 4; ++mi) {
      const long grow = r0 + wr * 64 + mi * 16 + fq * 4;
      #pragma unroll
      for (int r = 0; r < 4; ++r)
        C[(grow + r) * (long)N + gcol] = (half_t)(acc[mi][ni][r] + bv);
    }
  }
}

// ---------------- LSTM recurrence: AGPR-resident MFMA matvec, kc-outer ----------------
// 1 WG (256 thr, 4 waves, 1/SIMD) per batch. Wave w owns gate-w rows
// [w*256, w*256+256) = 16 row-tiles x 8 k-chunks. rts 0..11 reg-resident
// (96 frags -> AGPR), rts 12..15 in dynamic LDS. kc-outer loops give 8
// independent acc chains per group -> MFMA issue-bound, not latency-bound.

__global__ __launch_bounds__(256, 1) void k_lstm_v3(const half_t* __restrict__ xg,
                                                    const uint4* __restrict__ wqf,
                                                    half_t* __restrict__ hout,
                                                    float* __restrict__ c_state,
                                                    half_t* __restrict__ h_state,
                                                    int steps, int first) {
  extern __shared__ uint4 wlds[];                 // [4][LFRAGS3][64]
  __shared__ __align__(16) half_t hsh[2][256];
  __shared__ __align__(16) float gsh[1024];
  const int b = blockIdx.x;
  const int tid = threadIdx.x;
  const int w = tid >> 6, l = tid & 63;
  const int j = tid;
  const int q = l >> 4;

  // one-time residency: 96 frags -> registers (AGPR-backed), 32 -> LDS
  half8 wv[RFRAGS3];
  const uint4* wbase = wqf + (size_t)w * 128 * 64;
  #pragma unroll
  for (int i = 0; i < RFRAGS3; ++i)
    wv[i] = __builtin_bit_cast(half8, wbase[i * 64 + l]);
  #pragma unroll
  for (int i = 0; i < LFRAGS3; ++i)
    wlds[(w * LFRAGS3 + i) * 64 + l] = wbase[(RFRAGS3 + i) * 64 + l];

  float c = 0.f;
  if (first) {
    hsh[0][j] = (half_t)0.f;
  } else {
    hsh[0][j] = h_state[b * H_ + j];
    c = c_state[b * H_ + j];
  }
  __syncthreads();

  const half_t* xgb = xg + (long)b * steps * G4_;
  half_t* hp_out = hout + (long)b * steps * H_ + j;

  for (int t = 0; t < steps; ++t) {
    // xg preacts (issued early, consumed after MFMA phase)
    const half_t* xr = xgb + (long)t * G4_;
    float x0 = (float)xr[j];
    float x1 = (float)xr[256 + j];
    float x2 = (float)xr[512 + j];
    float x3 = (float)xr[768 + j];

    // B-frags: h(t-1) broadcast to all 16 cols (per-16-lane-group ds read)
    const half_t* hp = hsh[t & 1];
    half8 bf[8];
    #pragma unroll
    for (int kc = 0; kc < 8; ++kc)
      bf[kc] = *(const half8*)(hp + kc * 32 + (q << 3));

    floatx4 acc[8];

    // ---- group A: row-tiles 0..7, kc-outer -> 8 independent chains ----
    #pragma unroll
    for (int rt = 0; rt < 8; ++rt) acc[rt] = (floatx4){0.f, 0.f, 0.f, 0.f};
    #pragma unroll
    for (int kc = 0; kc < 8; ++kc)
      #pragma unroll
      for (int rt = 0; rt < 8; ++rt)
        acc[rt] = __builtin_amdgcn_mfma_f32_16x16x32_f16(wv[rt * 8 + kc], bf[kc], acc[rt], 0, 0, 0);
    if ((l & 15) == 0) {
      #pragma unroll
      for (int rt = 0; rt < 8; ++rt)
        *(floatx4*)&gsh[w * 256 + rt * 16 + (q << 2)] = acc[rt];
    }

    // ---- group B: row-tiles 8..15 (8..11 reg, 12..15 LDS), kc-outer ----
    #pragma unroll
    for (int rt = 0; rt < 8; ++rt) acc[rt] = (floatx4){0.f, 0.f, 0.f, 0.f};
    #pragma unroll
    for (int kc = 0; kc < 8; ++kc) {
      #pragma unroll
      for (int rt = 0; rt < 4; ++rt)
        acc[rt] = __builtin_amdgcn_mfma_f32_16x16x32_f16(wv[(8 + rt) * 8 + kc], bf[kc], acc[rt], 0, 0, 0);
      #pragma unroll
      for (int rt = 0; rt < 4; ++rt) {
        half8 wf = __builtin_bit_cast(half8, wlds[(w * LFRAGS3 + rt * 8 + kc) * 64 + l]);
        acc[4 + rt] = __builtin_amdgcn_mfma_f32_16x16x32_f16(wf, bf[kc], acc[4 + rt], 0, 0, 0);
      }
    }
    if ((l & 15) == 0) {
      #pragma unroll
      for (int rt = 0; rt < 8; ++rt)
        *(floatx4*)&gsh[w * 256 + (8 + rt) * 16 + (q << 2)] = acc[rt];
    }
    __syncthreads();                  // B1: gsh complete (and hsh[t&1] reads done)

    // thread-local gates for unit j (gate-major rows: i,f,g,o)
    float gi = gsh[j]       + x0;
    float gf = gsh[256 + j] + x1;
    float gg = gsh[512 + j] + x2;
    float go = gsh[768 + j] + x3;
    float ig = fast_sigmoid(gi);
    float fg = fast_sigmoid(gf);
    float g2 = fast_tanh(gg);
    float og = fast_sigmoid(go);
    c = fg * c + ig * g2;
    float h = og * fast_tanh(c);
    half_t hh = (half_t)h;
    hp_out[(long)t * H_] = hh;
    hsh[(t + 1) & 1][j] = hh;         // parity buffer
    __syncthreads();                  // B2: h(t) visible for step t+1
  }
  c_state[b * H_ + j] = c;
  h_state[b * H_ + j] = (half_t)hsh[steps & 1][j];
}

// ---------------- r3/r5 streaming recurrence (fallback) ----------------

__global__ __launch_bounds__(1024) void k_lstm(const half_t* __restrict__ xg,
                                               const uint4* __restrict__ Wp,
                                               half_t* __restrict__ hout,
                                               float* __restrict__ c_state,
                                               half_t* __restrict__ h_state,
                                               int steps, int first) {
  const int b = blockIdx.x;
  const int j = threadIdx.x;
  __shared__ float gsh[1024];
  __shared__ __align__(16) half_t hsh[256];
  float c = 0.f;
  if (j < H_) {
    if (first) {
      hsh[j] = (half_t)0.f;
    } else {
      hsh[j] = h_state[b * H_ + j];
      c = c_state[b * H_ + j];
    }
  }
  const uint4*  wp     = Wp + j;
  const half_t* xp     = xg + (long)b * steps * G4_ + j;
  half_t*       hp_out = hout + (long)b * steps * H_;
  for (int t = 0; t < steps; ++t) {
    __syncthreads();
    float acc = (float)xp[(long)t * G4_];
    const uint4* hv4 = (const uint4*)hsh;
    #pragma unroll 8
    for (int kc = 0; kc < 32; ++kc) {
      uint4 w  = wp[(long)kc * G4_];
      uint4 h4 = hv4[kc];
      acc = dot2acc(w.x, h4.x, acc);
      acc = dot2acc(w.y, h4.y, acc);
      acc = dot2acc(w.z, h4.z, acc);
      acc = dot2acc(w.w, h4.w, acc);
    }
    gsh[j] = acc;
    __syncthreads();
    if (j < H_) {
      float ig = fast_sigmoid(gsh[j]);
      float fg = fast_sigmoid(gsh[H_ + j]);
      float g2 = fast_tanh(gsh[2 * H_ + j]);
      float og = fast_sigmoid(gsh[3 * H_ + j]);
      c = fg * c + ig * g2;
      float h = og * fast_tanh(c);
      hp_out[(long)t * H_ + j] = (half_t)h;
      hsh[j] = (half_t)h;
    }
  }
  if (j < H_) {
    c_state[b * H_ + j] = c;
    h_state[b * H_ + j] = hsh[j];
  }
}

// ---------------- FC + softmax (unchanged) ----------------

__global__ __launch_bounds__(256) void k_fc_softmax(const half_t* __restrict__ h2,
                                                    const float* __restrict__ fcwt,
                                                    const float* __restrict__ fcb,
                                                    float* __restrict__ out,
                                                    int rowShift, int strideB, int toff) {
  const int lane = threadIdx.x & 63;
  const int r = blockIdx.x * 4 + (threadIdx.x >> 6);
  const half_t* hr = h2 + (long)r * H_;
  float acc = fcb[lane];
  for (int kc = 0; kc < 32; ++kc) {
    uint4 hv = *(const uint4*)(hr + kc * 8);
    unsigned hu[4] = {hv.x, hv.y, hv.z, hv.w};
    #pragma unroll
    for (int p = 0; p < 4; ++p) {
      half2t hh = __builtin_bit_cast(half2t, hu[p]);
      acc += (float)hh[0] * fcwt[(kc * 8 + p * 2) * 64 + lane];
      acc += (float)hh[1] * fcwt[(kc * 8 + p * 2 + 1) * 64 + lane];
    }
  }
  float m = acc;
  #pragma unroll
  for (int off = 32; off > 0; off >>= 1) m = fmaxf(m, __shfl_xor(m, off));
  float e = __expf(acc - m);
  float s = e;
  #pragma unroll
  for (int off = 32; off > 0; off >>= 1) s += __shfl_xor(s, off);
  const long outrow = (long)(r >> rowShift) * strideB + toff + (r & ((1 << rowShift) - 1));
  out[outrow * OUT_ + lane] = e / s;
}

// ---------------- launch ----------------

extern "C" void kernel_launch(void* const* d_in, const int* in_sizes, int n_in,
                              void* d_out, int out_size, void* d_ws, size_t ws_size,
                              hipStream_t stream) {
  const int*   x    = (const int*)d_in[0];
  const float* tab  = (const float*)d_in[1];
  const float* wih0 = (const float*)d_in[2];
  const float* whh0 = (const float*)d_in[3];
  const float* bih0 = (const float*)d_in[4];
  const float* bhh0 = (const float*)d_in[5];
  const float* wih1 = (const float*)d_in[6];
  const float* whh1 = (const float*)d_in[7];
  const float* bih1 = (const float*)d_in[8];
  const float* bhh1 = (const float*)d_in[9];
  const float* fcw  = (const float*)d_in[10];
  const float* fcb  = (const float*)d_in[11];

  char* p = (char*)d_ws;
  auto alloc = [&](size_t bytes) {
    void* r = (void*)p;
    p += (bytes + 255) & ~(size_t)255;
    return r;
  };
  half_t* wih0_h = (half_t*)alloc((size_t)G4_ * D_ * 2);
  half_t* wih1_h = (half_t*)alloc((size_t)G4_ * H_ * 2);
  half_t* wqf0   = (half_t*)alloc((size_t)G4_ * H_ * 2);   // frag pack
  half_t* wqf1   = (half_t*)alloc((size_t)G4_ * H_ * 2);
  half_t* wp0    = (half_t*)alloc((size_t)G4_ * H_ * 2);   // streaming pack (fallback)
  half_t* wp1    = (half_t*)alloc((size_t)G4_ * H_ * 2);
  float*  bias0  = (float*)alloc(G4_ * 4);
  float*  bias1  = (float*)alloc(G4_ * 4);
  float*  fcwt   = (float*)alloc((size_t)H_ * OUT_ * 4);
  half_t* hstate = (half_t*)alloc((size_t)2 * B_ * H_ * 2);
  float*  cstate = (float*)alloc((size_t)2 * B_ * H_ * 4);
  size_t fixed_used = (size_t)(p - (char*)d_ws);

  // Chunk length: largest power-of-2 CH <= 2048 with XG+HB fitting in ws.
  int CH = 2048;
  while (CH > 32 &&
         fixed_used + (size_t)CH * (131072 + 32768) + (1u << 20) > ws_size)
    CH >>= 1;
  const int rowShift = __builtin_ctz(CH);
  half_t* XG = (half_t*)alloc((size_t)CH * B_ * G4_ * 2);
  half_t* HB = (half_t*)alloc((size_t)CH * B_ * H_ * 2);
  half_t* ebuf = (half_t*)d_out;   // 32MB == out bytes; rows consumed before FC writes

  hipError_t attr_rc = hipFuncSetAttribute(
      reinterpret_cast<const void*>(k_lstm_v3),
      hipFuncAttributeMaxDynamicSharedMemorySize, LDS3_BYTES);
  const bool use_res = (attr_rc == hipSuccess);

  // prep (tiny)
  k_cvt_f16<<<512, 256, 0, stream>>>(wih0, wih0_h, G4_ * D_);
  k_cvt_f16<<<1024, 256, 0, stream>>>(wih1, wih1_h, G4_ * H_);
  k_pack_whh_frag<<<1024, 256, 0, stream>>>(whh0, wqf0);
  k_pack_whh_frag<<<1024, 256, 0, stream>>>(whh1, wqf1);
  k_pack_whh<<<1024, 256, 0, stream>>>(whh0, wp0);
  k_pack_whh<<<1024, 256, 0, stream>>>(whh1, wp1);
  k_bias<<<4, 256, 0, stream>>>(bih0, bhh0, bias0, G4_);
  k_bias<<<4, 256, 0, stream>>>(bih1, bhh1, bias1, G4_);
  k_fcwt<<<64, 256, 0, stream>>>(fcw, fcwt);

  k_embed<<<MTOT * (D_ / 8) / 256, 256, 0, stream>>>(x, tab, ebuf);

  const int M = B_ * CH;
  const int nchunks = T_ / CH;
  for (int ci = 0; ci < nchunks; ++ci) {
    const int t0 = ci * CH;
    k_gemm_f16<<<dim3(M / 128, G4_ / 128), 256, 0, stream>>>(
        ebuf, wih0_h, bias0, XG, D_, G4_, rowShift, T_, t0);
    if (use_res)
      k_lstm_v3<<<B_, 256, LDS3_BYTES, stream>>>(XG, (const uint4*)wqf0, HB,
                                                 cstate, hstate, CH, ci == 0);
    else
      k_lstm<<<B_, 1024, 0, stream>>>(XG, (const uint4*)wp0, HB,
                                      cstate, hstate, CH, ci == 0);
    k_gemm_f16<<<dim3(M / 128, G4_ / 128), 256, 0, stream>>>(
        HB, wih1_h, bias1, XG, H_, G4_, rowShift, CH, 0);
    if (use_res)
      k_lstm_v3<<<B_, 256, LDS3_BYTES, stream>>>(XG, (const uint4*)wqf1, HB,
                                                 cstate + B_ * H_, hstate + B_ * H_,
                                                 CH, ci == 0);
    else
      k_lstm<<<B_, 1024, 0, stream>>>(XG, (const uint4*)wp1, HB,
                                      cstate + B_ * H_, hstate + B_ * H_,
                                      CH, ci == 0);
    k_fc_softmax<<<M / 4, 256, 0, stream>>>(HB, fcwt, fcb, (float*)d_out,
                                            rowShift, T_, t0);
  }
}

// Round 9
// 7984.750 us; speedup vs baseline: 2.2603x; 1.2910x over previous
//
#include <hip/hip_runtime.h>
#include <cstdint>
#include <cstddef>

// ---------------------------------------------------------------------------
// LSTMModel: embed(mask pad=0) -> LSTM(128->256) -> LSTM(256->256) -> FC(256->64) -> softmax
// B=64 T=2048 D=128 H=256 4H=1024 OUT=64 V=1000
//
// Round 9: r7/r8 showed MFMA pipe = ~16cyc/MFMA with 1 wave/SIMD (2050cyc
// busy/step constant across both rounds, active-CU-corrected), plus ~3700cyc
// of un-overlapped serial phases. Fix: 8 waves (512thr, 2/SIMD) -> two
// feeders per MFMA pipe + cross-wave phase overlap. Each wave owns 128 rows:
// 48 frags in regs (192 VGPR, rts 0..5) + 16 frags in LDS (rts 6..7, 128KB
// dyn). Budget ~240 <= 256 @ 2 waves/SIMD (spill tripwire: WRITE_SIZE).
// Explicit cross-iteration xg prefetch (xc/xn swap). Same wqf pack as r7/r8
// (row mapping identical). Fallback: r3 streaming kernel if LDS attr fails.
//  - GEMM/embed/fc/chunking unchanged (passed, ~0.3ms total)
// ---------------------------------------------------------------------------

typedef _Float16 half_t;
typedef _Float16 half8 __attribute__((ext_vector_type(8)));
typedef _Float16 half2t __attribute__((ext_vector_type(2)));
typedef float floatx4 __attribute__((ext_vector_type(4)));

#define B_   64
#define T_   2048
#define D_   128
#define H_   256
#define G4_  1024
#define OUT_ 64
#define MTOT (B_ * T_)

#define RF4 48                           // reg-resident frags per wave (rts 0..5)
#define LF4 16                           // LDS-resident frags per wave (rts 6..7)
#define LDS4_BYTES (8 * LF4 * 64 * 16)   // 128 KB dynamic LDS

#if defined(__has_builtin)
#if __has_builtin(__builtin_amdgcn_fdot2)
#define HAVE_FDOT2 1
#endif
#endif

__device__ __forceinline__ float dot2acc(unsigned w, unsigned h, float acc) {
  half2t a = __builtin_bit_cast(half2t, w);
  half2t b = __builtin_bit_cast(half2t, h);
#ifdef HAVE_FDOT2
  return __builtin_amdgcn_fdot2(a, b, acc, false);
#else
  return acc + (float)a[0] * (float)b[0] + (float)a[1] * (float)b[1];
#endif
}

__device__ __forceinline__ float fast_sigmoid(float x) {
  return 1.f / (1.f + __expf(-x));
}
__device__ __forceinline__ float fast_tanh(float x) {
  return 1.f - 2.f / (1.f + __expf(2.f * x));
}

// ---------------- prep kernels ----------------

__global__ __launch_bounds__(256) void k_cvt_f16(const float* __restrict__ in,
                                                 half_t* __restrict__ out, int n) {
  int i = blockIdx.x * 256 + threadIdx.x;
  if (i < n) out[i] = (half_t)in[i];
}

// streaming pack (fallback kernel): wp[(kc*1024 + j)*8 + e] = Whh[j][kc*8+e]
__global__ __launch_bounds__(256) void k_pack_whh(const float* __restrict__ whh,
                                                  half_t* __restrict__ wp) {
  int i = blockIdx.x * 256 + threadIdx.x;      // 262144 total
  int e  = i & 7;
  int j  = (i >> 3) & 1023;
  int kc = i >> 13;
  wp[i] = (half_t)whh[j * 256 + kc * 8 + e];
}

// MFMA A-frag pack (same as r7/r8): f = w4*128 + rt16*8 + kc, lane l, elem e:
// wqf[(f*64 + l)*8 + e] = Whh[w4*256 + rt16*16 + (l&15)][kc*32 + (l>>4)*8 + e]
__global__ __launch_bounds__(256) void k_pack_whh_frag(const float* __restrict__ whh,
                                                       half_t* __restrict__ wqf) {
  int i = blockIdx.x * 256 + threadIdx.x;      // 262144 total
  int e  = i & 7;
  int l  = (i >> 3) & 63;
  int kc = (i >> 9) & 7;
  int rt = (i >> 12) & 15;
  int w  = (i >> 16) & 3;
  int row = w * 256 + rt * 16 + (l & 15);
  int col = kc * 32 + (l >> 4) * 8 + e;
  wqf[i] = (half_t)whh[row * 256 + col];
}

__global__ __launch_bounds__(256) void k_bias(const float* __restrict__ a,
                                              const float* __restrict__ b,
                                              float* __restrict__ out, int n) {
  int i = blockIdx.x * 256 + threadIdx.x;
  if (i < n) out[i] = a[i] + b[i];
}

// fc_W [64][256] -> fcwt[k*64 + l] = fc_W[l][k]
__global__ __launch_bounds__(256) void k_fcwt(const float* __restrict__ fcw,
                                              float* __restrict__ fcwt) {
  int i = blockIdx.x * 256 + threadIdx.x;      // 16384 total
  fcwt[i] = fcw[(i & 63) * 256 + (i >> 6)];
}

// ---------------- embedding ----------------

__global__ __launch_bounds__(256) void k_embed(const int* __restrict__ x,
                                               const float* __restrict__ tab,
                                               half_t* __restrict__ e) {
  const long i = (long)blockIdx.x * 256 + threadIdx.x;
  const long m = i >> 4;
  const int ch = (int)(i & 15) * 8;
  const int xi = x[m];
  half8 v;
  #pragma unroll
  for (int q = 0; q < 8; ++q) v[q] = (half_t)0.f;
  if (xi != 0) {
    const float* p = tab + (long)xi * D_ + ch;
    #pragma unroll
    for (int q = 0; q < 8; ++q) v[q] = (half_t)p[q];
  }
  *(half8*)(e + m * D_ + ch) = v;
}

// ---------------- f16 MFMA GEMM (unchanged, passed) ----------------

__global__ __launch_bounds__(256) void k_gemm_f16(const half_t* __restrict__ A,
                                                  const half_t* __restrict__ Wt,
                                                  const float* __restrict__ bias,
                                                  half_t* __restrict__ C,
                                                  int K, int N,
                                                  int rowShift, int strideB, int toff) {
  __shared__ half_t As[128][40];
  __shared__ half_t Bs[128][40];
  const int tid  = threadIdx.x;
  const int lane = tid & 63;
  const int wave = tid >> 6;
  const int wr = wave >> 1, wc = wave & 1;
  const int r0 = blockIdx.x * 128;
  const int n0 = blockIdx.y * 128;
  const int srow = tid >> 2;
  const int schunk = (tid & 3) * 8;
  const int rmask = (1 << rowShift) - 1;

  floatx4 zero = {0.f, 0.f, 0.f, 0.f};
  floatx4 acc[4][4];
  for (int i = 0; i < 4; ++i)
    for (int j = 0; j < 4; ++j) acc[i][j] = zero;

  const int ra = r0 + srow, rb = r0 + srow + 64;
  const half_t* ArowA = A + ((long)(ra >> rowShift) * strideB + toff + (ra & rmask)) * K;
  const half_t* ArowB = A + ((long)(rb >> rowShift) * strideB + toff + (rb & rmask)) * K;

  for (int k0 = 0; k0 < K; k0 += 32) {
    *(uint4*)(&As[srow][schunk])      = *(const uint4*)(ArowA + k0 + schunk);
    *(uint4*)(&As[srow + 64][schunk]) = *(const uint4*)(ArowB + k0 + schunk);
    const half_t* Bp = Wt + (long)(n0 + srow) * K + k0 + schunk;
    *(uint4*)(&Bs[srow][schunk])      = *(const uint4*)(Bp);
    *(uint4*)(&Bs[srow + 64][schunk]) = *(const uint4*)(Bp + 64L * K);
    __syncthreads();

    const int kq = (lane >> 4) * 8;
    const int fr = lane & 15;
    half8 af[4], bf[4];
    #pragma unroll
    for (int i = 0; i < 4; ++i) af[i] = *(const half8*)(&As[wr * 64 + i * 16 + fr][kq]);
    #pragma unroll
    for (int i = 0; i < 4; ++i) bf[i] = *(const half8*)(&Bs[wc * 64 + i * 16 + fr][kq]);
    #pragma unroll
    for (int mi = 0; mi < 4; ++mi)
      #pragma unroll
      for (int ni = 0; ni < 4; ++ni)
        acc[mi][ni] = __builtin_amdgcn_mfma_f32_16x16x32_f16(af[mi], bf[ni], acc[mi][ni], 0, 0, 0);
    __syncthreads();
  }

  const int fr = lane & 15, fq = lane >> 4;
  for (int ni = 0; ni < 4; ++ni) {
    const int gcol = n0 + wc * 64 + ni * 16 + fr;
    const float bv = bias[gcol];
    for (int mi = 0; mi < 4; ++mi) {
      const long grow = r0 + wr * 64 + mi * 16 + fq * 4;
      #pragma unroll
      for (int r = 0; r < 4; ++r)
        C[(grow + r) * (long)N + gcol] = (half_t)(acc[mi][ni][r] + bv);
    }
  }
}

// ---------------- LSTM recurrence: 8 waves, 2/SIMD, resident weights ----------------
// 1 WG (512 thr) per batch. Wave w owns rows [w*128, (w+1)*128) of the
// gate-major [1024] row space: 8 row-tiles x 8 kc. rts 0..5 reg-resident
// (48 frags), rts 6..7 in dynamic LDS. Two waves per SIMD keep the MFMA
// pipe fed (~8cyc/op vs 16 single-wave) and overlap VALU/LDS phases.

__global__ __launch_bounds__(512, 2) void k_lstm_v4(const half_t* __restrict__ xg,
                                                    const uint4* __restrict__ wqf,
                                                    half_t* __restrict__ hout,
                                                    float* __restrict__ c_state,
                                                    half_t* __restrict__ h_state,
                                                    int steps, int first) {
  extern __shared__ uint4 wlds[];                 // [8][LF4][64]
  __shared__ __align__(16) half_t hsh[2][256];
  __shared__ __align__(16) float gsh[1024];
  const int b = blockIdx.x;
  const int tid = threadIdx.x;
  const int w = tid >> 6, l = tid & 63;
  const int q = l >> 4;

  // residency: f_old(w,rt,kc) = (w>>1)*128 + ((w&1)*8 + rt)*8 + kc
  //  -> wave-local frag i = rt*8+kc, base offset (w>>1)*128 + (w&1)*64
  const uint4* wbase = wqf + ((size_t)(w >> 1) * 128 + (size_t)(w & 1) * 64) * 64;
  half8 wv[RF4];
  #pragma unroll
  for (int i = 0; i < RF4; ++i)                 // rts 0..5
    wv[i] = __builtin_bit_cast(half8, wbase[i * 64 + l]);
  #pragma unroll
  for (int i = 0; i < LF4; ++i)                 // rts 6..7
    wlds[(w * LF4 + i) * 64 + l] = wbase[(RF4 + i) * 64 + l];

  float c = 0.f;
  float xc0 = 0.f, xc1 = 0.f, xc2 = 0.f, xc3 = 0.f;
  const half_t* xgb = xg + (long)b * steps * G4_;
  if (tid < 256) {
    if (first) {
      hsh[0][tid] = (half_t)0.f;
    } else {
      hsh[0][tid] = h_state[b * H_ + tid];
      c = c_state[b * H_ + tid];
    }
    xc0 = (float)xgb[tid];
    xc1 = (float)xgb[256 + tid];
    xc2 = (float)xgb[512 + tid];
    xc3 = (float)xgb[768 + tid];
  }
  __syncthreads();

  half_t* hp_out = hout + (long)b * steps * H_ + tid;

  for (int t = 0; t < steps; ++t) {
    // prefetch next step's preacts (consumed next iteration's gate phase)
    float xn0 = 0.f, xn1 = 0.f, xn2 = 0.f, xn3 = 0.f;
    if (tid < 256) {
      const half_t* xrn = xgb + (long)((t + 1 < steps) ? t + 1 : t) * G4_;
      xn0 = (float)xrn[tid];
      xn1 = (float)xrn[256 + tid];
      xn2 = (float)xrn[512 + tid];
      xn3 = (float)xrn[768 + tid];
    }

    const half_t* hp = hsh[t & 1];
    floatx4 acc[4];

    // ---- group A: local rts 0..3 (all reg) ----
    #pragma unroll
    for (int i = 0; i < 4; ++i) acc[i] = (floatx4){0.f, 0.f, 0.f, 0.f};
    #pragma unroll
    for (int kb = 0; kb < 2; ++kb) {
      half8 bf4[4];
      #pragma unroll
      for (int kk = 0; kk < 4; ++kk)
        bf4[kk] = *(const half8*)(hp + (kb * 4 + kk) * 32 + (q << 3));
      #pragma unroll
      for (int kk = 0; kk < 4; ++kk)
        #pragma unroll
        for (int rt = 0; rt < 4; ++rt)
          acc[rt] = __builtin_amdgcn_mfma_f32_16x16x32_f16(
              wv[rt * 8 + kb * 4 + kk], bf4[kk], acc[rt], 0, 0, 0);
    }
    if ((l & 15) == 0) {
      #pragma unroll
      for (int rt = 0; rt < 4; ++rt)
        *(floatx4*)&gsh[w * 128 + rt * 16 + (q << 2)] = acc[rt];
    }

    // ---- group B: local rts 4..7 (4,5 reg; 6,7 LDS) ----
    #pragma unroll
    for (int i = 0; i < 4; ++i) acc[i] = (floatx4){0.f, 0.f, 0.f, 0.f};
    #pragma unroll
    for (int kb = 0; kb < 2; ++kb) {
      half8 bf4[4];
      #pragma unroll
      for (int kk = 0; kk < 4; ++kk)
        bf4[kk] = *(const half8*)(hp + (kb * 4 + kk) * 32 + (q << 3));
      #pragma unroll
      for (int kk = 0; kk < 4; ++kk) {
        const int kc = kb * 4 + kk;
        #pragma unroll
        for (int rt = 0; rt < 2; ++rt)
          acc[rt] = __builtin_amdgcn_mfma_f32_16x16x32_f16(
              wv[(4 + rt) * 8 + kc], bf4[kk], acc[rt], 0, 0, 0);
        #pragma unroll
        for (int rt = 0; rt < 2; ++rt) {
          half8 wf = __builtin_bit_cast(half8,
              wlds[(w * LF4 + rt * 8 + kc) * 64 + l]);
          acc[2 + rt] = __builtin_amdgcn_mfma_f32_16x16x32_f16(
              wf, bf4[kk], acc[2 + rt], 0, 0, 0);
        }
      }
    }
    if ((l & 15) == 0) {
      #pragma unroll
      for (int rt = 0; rt < 4; ++rt)
        *(floatx4*)&gsh[w * 128 + (4 + rt) * 16 + (q << 2)] = acc[rt];
    }
    __syncthreads();                  // B1: gsh complete, hsh[t&1] reads done

    if (tid < 256) {
      float gi = gsh[tid]       + xc0;
      float gf = gsh[256 + tid] + xc1;
      float gg = gsh[512 + tid] + xc2;
      float go = gsh[768 + tid] + xc3;
      float ig = fast_sigmoid(gi);
      float fg = fast_sigmoid(gf);
      float g2 = fast_tanh(gg);
      float og = fast_sigmoid(go);
      c = fg * c + ig * g2;
      float h = og * fast_tanh(c);
      half_t hh = (half_t)h;
      hp_out[(long)t * H_] = hh;
      hsh[(t + 1) & 1][tid] = hh;     // parity buffer
    }
    xc0 = xn0; xc1 = xn1; xc2 = xn2; xc3 = xn3;
    __syncthreads();                  // B2: h(t) visible for step t+1
  }
  if (tid < 256) {
    c_state[b * H_ + tid] = c;
    h_state[b * H_ + tid] = hsh[steps & 1][tid];
  }
}

// ---------------- r3/r5 streaming recurrence (fallback) ----------------

__global__ __launch_bounds__(1024) void k_lstm(const half_t* __restrict__ xg,
                                               const uint4* __restrict__ Wp,
                                               half_t* __restrict__ hout,
                                               float* __restrict__ c_state,
                                               half_t* __restrict__ h_state,
                                               int steps, int first) {
  const int b = blockIdx.x;
  const int j = threadIdx.x;
  __shared__ float gsh[1024];
  __shared__ __align__(16) half_t hsh[256];
  float c = 0.f;
  if (j < H_) {
    if (first) {
      hsh[j] = (half_t)0.f;
    } else {
      hsh[j] = h_state[b * H_ + j];
      c = c_state[b * H_ + j];
    }
  }
  const uint4*  wp     = Wp + j;
  const half_t* xp     = xg + (long)b * steps * G4_ + j;
  half_t*       hp_out = hout + (long)b * steps * H_;
  for (int t = 0; t < steps; ++t) {
    __syncthreads();
    float acc = (float)xp[(long)t * G4_];
    const uint4* hv4 = (const uint4*)hsh;
    #pragma unroll 8
    for (int kc = 0; kc < 32; ++kc) {
      uint4 w  = wp[(long)kc * G4_];
      uint4 h4 = hv4[kc];
      acc = dot2acc(w.x, h4.x, acc);
      acc = dot2acc(w.y, h4.y, acc);
      acc = dot2acc(w.z, h4.z, acc);
      acc = dot2acc(w.w, h4.w, acc);
    }
    gsh[j] = acc;
    __syncthreads();
    if (j < H_) {
      float ig = fast_sigmoid(gsh[j]);
      float fg = fast_sigmoid(gsh[H_ + j]);
      float g2 = fast_tanh(gsh[2 * H_ + j]);
      float og = fast_sigmoid(gsh[3 * H_ + j]);
      c = fg * c + ig * g2;
      float h = og * fast_tanh(c);
      hp_out[(long)t * H_ + j] = (half_t)h;
      hsh[j] = (half_t)h;
    }
  }
  if (j < H_) {
    c_state[b * H_ + j] = c;
    h_state[b * H_ + j] = hsh[j];
  }
}

// ---------------- FC + softmax (unchanged) ----------------

__global__ __launch_bounds__(256) void k_fc_softmax(const half_t* __restrict__ h2,
                                                    const float* __restrict__ fcwt,
                                                    const float* __restrict__ fcb,
                                                    float* __restrict__ out,
                                                    int rowShift, int strideB, int toff) {
  const int lane = threadIdx.x & 63;
  const int r = blockIdx.x * 4 + (threadIdx.x >> 6);
  const half_t* hr = h2 + (long)r * H_;
  float acc = fcb[lane];
  for (int kc = 0; kc < 32; ++kc) {
    uint4 hv = *(const uint4*)(hr + kc * 8);
    unsigned hu[4] = {hv.x, hv.y, hv.z, hv.w};
    #pragma unroll
    for (int p = 0; p < 4; ++p) {
      half2t hh = __builtin_bit_cast(half2t, hu[p]);
      acc += (float)hh[0] * fcwt[(kc * 8 + p * 2) * 64 + lane];
      acc += (float)hh[1] * fcwt[(kc * 8 + p * 2 + 1) * 64 + lane];
    }
  }
  float m = acc;
  #pragma unroll
  for (int off = 32; off > 0; off >>= 1) m = fmaxf(m, __shfl_xor(m, off));
  float e = __expf(acc - m);
  float s = e;
  #pragma unroll
  for (int off = 32; off > 0; off >>= 1) s += __shfl_xor(s, off);
  const long outrow = (long)(r >> rowShift) * strideB + toff + (r & ((1 << rowShift) - 1));
  out[outrow * OUT_ + lane] = e / s;
}

// ---------------- launch ----------------

extern "C" void kernel_launch(void* const* d_in, const int* in_sizes, int n_in,
                              void* d_out, int out_size, void* d_ws, size_t ws_size,
                              hipStream_t stream) {
  const int*   x    = (const int*)d_in[0];
  const float* tab  = (const float*)d_in[1];
  const float* wih0 = (const float*)d_in[2];
  const float* whh0 = (const float*)d_in[3];
  const float* bih0 = (const float*)d_in[4];
  const float* bhh0 = (const float*)d_in[5];
  const float* wih1 = (const float*)d_in[6];
  const float* whh1 = (const float*)d_in[7];
  const float* bih1 = (const float*)d_in[8];
  const float* bhh1 = (const float*)d_in[9];
  const float* fcw  = (const float*)d_in[10];
  const float* fcb  = (const float*)d_in[11];

  char* p = (char*)d_ws;
  auto alloc = [&](size_t bytes) {
    void* r = (void*)p;
    p += (bytes + 255) & ~(size_t)255;
    return r;
  };
  half_t* wih0_h = (half_t*)alloc((size_t)G4_ * D_ * 2);
  half_t* wih1_h = (half_t*)alloc((size_t)G4_ * H_ * 2);
  half_t* wqf0   = (half_t*)alloc((size_t)G4_ * H_ * 2);   // frag pack
  half_t* wqf1   = (half_t*)alloc((size_t)G4_ * H_ * 2);
  half_t* wp0    = (half_t*)alloc((size_t)G4_ * H_ * 2);   // streaming pack (fallback)
  half_t* wp1    = (half_t*)alloc((size_t)G4_ * H_ * 2);
  float*  bias0  = (float*)alloc(G4_ * 4);
  float*  bias1  = (float*)alloc(G4_ * 4);
  float*  fcwt   = (float*)alloc((size_t)H_ * OUT_ * 4);
  half_t* hstate = (half_t*)alloc((size_t)2 * B_ * H_ * 2);
  float*  cstate = (float*)alloc((size_t)2 * B_ * H_ * 4);
  size_t fixed_used = (size_t)(p - (char*)d_ws);

  // Chunk length: largest power-of-2 CH <= 2048 with XG+HB fitting in ws.
  int CH = 2048;
  while (CH > 32 &&
         fixed_used + (size_t)CH * (131072 + 32768) + (1u << 20) > ws_size)
    CH >>= 1;
  const int rowShift = __builtin_ctz(CH);
  half_t* XG = (half_t*)alloc((size_t)CH * B_ * G4_ * 2);
  half_t* HB = (half_t*)alloc((size_t)CH * B_ * H_ * 2);
  half_t* ebuf = (half_t*)d_out;   // 32MB == out bytes; rows consumed before FC writes

  hipError_t attr_rc = hipFuncSetAttribute(
      reinterpret_cast<const void*>(k_lstm_v4),
      hipFuncAttributeMaxDynamicSharedMemorySize, LDS4_BYTES);
  const bool use_res = (attr_rc == hipSuccess);

  // prep (tiny)
  k_cvt_f16<<<512, 256, 0, stream>>>(wih0, wih0_h, G4_ * D_);
  k_cvt_f16<<<1024, 256, 0, stream>>>(wih1, wih1_h, G4_ * H_);
  k_pack_whh_frag<<<1024, 256, 0, stream>>>(whh0, wqf0);
  k_pack_whh_frag<<<1024, 256, 0, stream>>>(whh1, wqf1);
  k_pack_whh<<<1024, 256, 0, stream>>>(whh0, wp0);
  k_pack_whh<<<1024, 256, 0, stream>>>(whh1, wp1);
  k_bias<<<4, 256, 0, stream>>>(bih0, bhh0, bias0, G4_);
  k_bias<<<4, 256, 0, stream>>>(bih1, bhh1, bias1, G4_);
  k_fcwt<<<64, 256, 0, stream>>>(fcw, fcwt);

  k_embed<<<MTOT * (D_ / 8) / 256, 256, 0, stream>>>(x, tab, ebuf);

  const int M = B_ * CH;
  const int nchunks = T_ / CH;
  for (int ci = 0; ci < nchunks; ++ci) {
    const int t0 = ci * CH;
    k_gemm_f16<<<dim3(M / 128, G4_ / 128), 256, 0, stream>>>(
        ebuf, wih0_h, bias0, XG, D_, G4_, rowShift, T_, t0);
    if (use_res)
      k_lstm_v4<<<B_, 512, LDS4_BYTES, stream>>>(XG, (const uint4*)wqf0, HB,
                                                 cstate, hstate, CH, ci == 0);
    else
      k_lstm<<<B_, 1024, 0, stream>>>(XG, (const uint4*)wp0, HB,
                                      cstate, hstate, CH, ci == 0);
    k_gemm_f16<<<dim3(M / 128, G4_ / 128), 256, 0, stream>>>(
        HB, wih1_h, bias1, XG, H_, G4_, rowShift, CH, 0);
    if (use_res)
      k_lstm_v4<<<B_, 512, LDS4_BYTES, stream>>>(XG, (const uint4*)wqf1, HB,
                                                 cstate + B_ * H_, hstate + B_ * H_,
                                                 CH, ci == 0);
    else
      k_lstm<<<B_, 1024, 0, stream>>>(XG, (const uint4*)wp1, HB,
                                      cstate + B_ * H_, hstate + B_ * H_,
                                      CH, ci == 0);
    k_fc_softmax<<<M / 4, 256, 0, stream>>>(HB, fcwt, fcb, (float*)d_out,
                                            rowShift, T_, t0);
  }
}